// Round 6
// baseline (175.676 us; speedup 1.0000x reference)
//
#include <hip/hip_runtime.h>
#include <hip/hip_bf16.h>

typedef __bf16 bf16x8 __attribute__((ext_vector_type(8)));
typedef __bf16 bf16x4 __attribute__((ext_vector_type(4)));
typedef float f32x4 __attribute__((ext_vector_type(4)));

#define FEAT 2048
#define HID  1024
#define AD   512
#define NB   128
#define NP   196
#define MROWS (NB * NP)      // 25088
#define BM 128
#define BN 128
#define BK 64
#define NSTEP (FEAT / BK)    // 32
#define NBLK (MROWS / BM * 4) // 196 row-tiles x 4 n-quarters = 784

// ---------------- pack We (fp32 [512][2048]) -> bf16 MFMA-fragment order ----------------
// For 16x16x32 MFMA, B-operand lane l needs We[nt*16 + (l&15)][kt*32 + (l>>4)*8 + e].
// Packed: off = ((kt*32 + nt)*64 + l)*8 + e  -> each (kt,nt) fragment is 1KB contiguous.
__global__ __launch_bounds__(256) void pack_we_k(const float* __restrict__ We,
                                                 __bf16* __restrict__ Bp) {
    int t = blockIdx.x * 256 + threadIdx.x;   // 131072 threads, 8 elems each
    int a  = t >> 8;
    int f0 = (t & 255) << 3;
    const float4* src = reinterpret_cast<const float4*>(We + ((size_t)a << 11) + f0);
    float4 x0 = src[0], x1 = src[1];
    int nt = a >> 4, r = a & 15;
    int kt = f0 >> 5, g = (f0 >> 3) & 3;
    size_t off = (((size_t)(kt * 32 + nt) * 64) + (r + (g << 4))) << 3;
    union { __bf16 h[8]; bf16x8 v; } u;
    u.h[0] = (__bf16)x0.x; u.h[1] = (__bf16)x0.y; u.h[2] = (__bf16)x0.z; u.h[3] = (__bf16)x0.w;
    u.h[4] = (__bf16)x1.x; u.h[5] = (__bf16)x1.y; u.h[6] = (__bf16)x1.z; u.h[7] = (__bf16)x1.w;
    *reinterpret_cast<bf16x8*>(Bp + off) = u.v;
}

// ---------------- dec[b][n] = hidden[b]·Wd[n] + bd[n] + be[n]  (fp32, exact) ------------
__global__ __launch_bounds__(256) void dec_k(const float* __restrict__ hidden,
                                             const float* __restrict__ Wd,
                                             const float* __restrict__ bd,
                                             const float* __restrict__ be,
                                             float* __restrict__ decb) {
    __shared__ float w[8][1028];
    const int tid = threadIdx.x;
    const int n0 = blockIdx.x << 3;
    const float4* wsrc = reinterpret_cast<const float4*>(Wd + ((size_t)n0 << 10));
    #pragma unroll
    for (int i = 0; i < 8; ++i)
        *reinterpret_cast<float4*>(&w[i][tid << 2]) = wsrc[(i << 8) + tid];
    __syncthreads();
    const int nl = tid & 7, b0 = tid >> 3;
    float acc[4] = {0.f, 0.f, 0.f, 0.f};
    const float4* wp = reinterpret_cast<const float4*>(&w[nl][0]);
    #pragma unroll 2
    for (int k4 = 0; k4 < 256; ++k4) {
        float4 wv = wp[k4];
        #pragma unroll
        for (int i = 0; i < 4; ++i) {
            const float4 h = reinterpret_cast<const float4*>(
                hidden + ((size_t)(b0 + (i << 5)) << 10))[k4];
            acc[i] = fmaf(wv.x, h.x, acc[i]);
            acc[i] = fmaf(wv.y, h.y, acc[i]);
            acc[i] = fmaf(wv.z, h.z, acc[i]);
            acc[i] = fmaf(wv.w, h.w, acc[i]);
        }
    }
    const float bias = bd[n0 + nl] + be[n0 + nl];
    #pragma unroll
    for (int i = 0; i < 4; ++i)
        decb[(size_t)(b0 + (i << 5)) * AD + n0 + nl] = acc[i] + bias;
}

// ---------------- main fused kernel helpers ----------------
__device__ __forceinline__ void load_a(const float* g, float4 r[8]) {
    #pragma unroll
    for (int i = 0; i < 8; ++i)
        r[i] = *reinterpret_cast<const float4*>(g + (size_t)(i * 16) * FEAT);
}

__device__ __forceinline__ void write_a(char* base, int srow, int schk, const float4 r[8]) {
    #pragma unroll
    for (int i = 0; i < 8; ++i) {
        const int rr = srow + 16 * i;
        union { __bf16 h[4]; bf16x4 v; } p;
        p.h[0] = (__bf16)r[i].x; p.h[1] = (__bf16)r[i].y;
        p.h[2] = (__bf16)r[i].z; p.h[3] = (__bf16)r[i].w;
        *reinterpret_cast<bf16x4*>(base + rr * 128 + ((schk * 8) ^ ((rr & 7) << 4))) = p.v;
    }
}

__device__ __forceinline__ void load_b(const __bf16* bs, bf16x8 f[8]) {
    #pragma unroll
    for (int kt2 = 0; kt2 < 2; ++kt2)
        #pragma unroll
        for (int j = 0; j < 4; ++j)
            f[kt2 * 4 + j] = *reinterpret_cast<const bf16x8*>(bs + kt2 * 16384 + j * 512);
}

__device__ __forceinline__ void mfma_step(const char* buf, const bf16x8 f[8],
                                          int wm, int lr, int lg, int rswz,
                                          f32x4 acc[4][4]) {
    #pragma unroll
    for (int kt2 = 0; kt2 < 2; ++kt2) {
        #pragma unroll
        for (int mt = 0; mt < 4; ++mt) {
            const int R = wm * 64 + mt * 16 + lr;
            bf16x8 a = *reinterpret_cast<const bf16x8*>(
                buf + R * 128 + ((kt2 * 64 + lg * 16) ^ rswz));
            acc[mt][0] = __builtin_amdgcn_mfma_f32_16x16x32_bf16(a, f[kt2*4+0], acc[mt][0], 0, 0, 0);
            acc[mt][1] = __builtin_amdgcn_mfma_f32_16x16x32_bf16(a, f[kt2*4+1], acc[mt][1], 0, 0, 0);
            acc[mt][2] = __builtin_amdgcn_mfma_f32_16x16x32_bf16(a, f[kt2*4+2], acc[mt][2], 0, 0, 0);
            acc[mt][3] = __builtin_amdgcn_mfma_f32_16x16x32_bf16(a, f[kt2*4+3], acc[mt][3], 0, 0, 0);
        }
    }
}

// ---------------- main fused kernel: enc GEMM + tanh + Wf-dot -> partial scores ---------
// Pipeline (one raw s_barrier per step; loads SURVIVE barriers — no vmcnt(0) drains):
//   step t: issue B(t+1)->reg bank; issue A(t+2)->reg bank (freed at t-1);
//           MFMA on LDS buf[t&1] with pre-loaded B regs;  cvt+ds_write A(t+1) late;
//           s_waitcnt lgkmcnt(0); s_barrier.
// A latency budget ~1.8 steps (HBM ~900cy ok); B ~1 step (L2 ~300cy ok).
__global__ __launch_bounds__(256, 2) void enc_score_k(
        const float* __restrict__ X, const __bf16* __restrict__ Bp,
        const float* __restrict__ decb, const float* __restrict__ Wf,
        float* __restrict__ spart) {
    __shared__ char Asm0[BM * BK * 2];        // 16 KB buffer 0
    __shared__ char Asm1[BM * BK * 2];        // 16 KB buffer 1
    __shared__ float swave[2][BM];
    const int tid  = threadIdx.x;
    const int wave = tid >> 6, lane = tid & 63;
    const int lr = lane & 15, lg = lane >> 4;
    const int wm = wave >> 1, wn = wave & 1;  // wave -> 64x64 quadrant
    // chunked XCD swizzle (784 = 8*98, bijective): same row-stripe stays on one XCD
    const int vbid = (blockIdx.x & 7) * 98 + (blockIdx.x >> 3);
    const int rt = vbid >> 2, nq = vbid & 3;
    const int row0 = rt * BM;
    const int ncol0 = nq * BN + wn * 64;      // this wave's global N base

    // acc init = dec[b][n]  (C/D layout: col=lane&15, row=(lane>>4)*4+j)
    f32x4 acc[4][4];
    #pragma unroll
    for (int mt = 0; mt < 4; ++mt) {
        #pragma unroll
        for (int j = 0; j < 4; ++j) {
            const int row = wm * 64 + mt * 16 + lg * 4 + j;
            const int b = (unsigned)(row0 + row) / 196u;
            const float* dp = decb + (size_t)b * AD + ncol0 + lr;
            #pragma unroll
            for (int nt = 0; nt < 4; ++nt) acc[mt][nt][j] = dp[nt * 16];
        }
    }

    // A staging (wave-contiguous): instr i covers rows (tid>>4)+16i, chunk (tid&15)*16B
    const int srow = tid >> 4;
    const int schk = tid & 15;
    const float* gA = X + (size_t)(row0 + srow) * FEAT + schk * 4;
    const int rswz = (lr & 7) << 4;
    // B fragments: packed Bp, frag(kt,nt) at byte (kt*32+nt)*1024 + lane*16
    const __bf16* Bq = Bp + ((size_t)(nq * 8 + wn * 4) << 9) + (lane << 3);

    float4 rAa[8], rAb[8];      // A reg banks: A(i) lives in bank (i&1)
    bf16x8 bfrA[8], bfrB[8];    // B reg banks: B(t) in bank (t&1) (A=even)

    // ---- prologue: A(0)->rAa, A(1)->rAb, B(0)->bfrA; write A(0)->buf0 ----
    load_a(gA, rAa);
    load_a(gA + BK, rAb);
    load_b(Bq, bfrA);
    write_a(Asm0, srow, schk, rAa);           // compiler waits A(0) (counted vmcnt)
    asm volatile("s_waitcnt lgkmcnt(0)" ::: "memory");
    __builtin_amdgcn_sched_barrier(0);
    __builtin_amdgcn_s_barrier();

    #pragma unroll 1
    for (int t2 = 0; t2 < NSTEP; t2 += 2) {
        // ======== even step t = t2: read buf0 (A(t2)), B from bfrA ========
        load_b(Bq + (size_t)(t2 + 1) * 32768, bfrB);            // B(t+1)
        if (t2 + 2 < NSTEP) load_a(gA + (size_t)(t2 + 2) * BK, rAa);  // A(t+2)
        __builtin_amdgcn_sched_barrier(0);
        mfma_step(Asm0, bfrA, wm, lr, lg, rswz, acc);
        __builtin_amdgcn_sched_barrier(0);
        write_a(Asm1, srow, schk, rAb);                          // A(t+1) late
        asm volatile("s_waitcnt lgkmcnt(0)" ::: "memory");
        __builtin_amdgcn_sched_barrier(0);
        __builtin_amdgcn_s_barrier();
        // ======== odd step t = t2+1: read buf1 (A(t2+1)), B from bfrB ========
        if (t2 + 2 < NSTEP) load_b(Bq + (size_t)(t2 + 2) * 32768, bfrA);  // B(t+1)
        if (t2 + 3 < NSTEP) load_a(gA + (size_t)(t2 + 3) * BK, rAb);      // A(t+2)
        __builtin_amdgcn_sched_barrier(0);
        mfma_step(Asm1, bfrB, wm, lr, lg, rswz, acc);
        if (t2 + 2 < NSTEP) {
            __builtin_amdgcn_sched_barrier(0);
            write_a(Asm0, srow, schk, rAa);                      // A(t+2)... = A(t2+2)
            asm volatile("s_waitcnt lgkmcnt(0)" ::: "memory");
            __builtin_amdgcn_sched_barrier(0);
            __builtin_amdgcn_s_barrier();
        }
    }

    // epilogue: partial score = sum_{n in this 128-col quarter} tanh(acc)*Wf[n]
    float wf[4];
    #pragma unroll
    for (int nt = 0; nt < 4; ++nt) wf[nt] = Wf[ncol0 + nt * 16 + lr];
    #pragma unroll
    for (int mt = 0; mt < 4; ++mt) {
        #pragma unroll
        for (int j = 0; j < 4; ++j) {
            float s = 0.f;
            #pragma unroll
            for (int nt = 0; nt < 4; ++nt) {
                float x = acc[mt][nt][j];
                float e = __expf(2.0f * x);
                float t = 1.0f - 2.0f / (e + 1.0f);   // tanh, no-NaN at +/-inf
                s = fmaf(t, wf[nt], s);
            }
            s += __shfl_xor(s, 1); s += __shfl_xor(s, 2);
            s += __shfl_xor(s, 4); s += __shfl_xor(s, 8);
            if (lr == 0) swave[wn][wm * 64 + mt * 16 + lg * 4 + j] = s;
        }
    }
    __syncthreads();
    if (tid < BM)
        spart[(size_t)nq * MROWS + row0 + tid] = swave[0][tid] + swave[1][tid];
}

// ---------------- softmax over P=196 per batch row (sums 4 N-quarter partials) ----------
__global__ __launch_bounds__(64) void softmax_k(const float* __restrict__ spart,
                                                float* __restrict__ alpha) {
    const int b = blockIdx.x, lane = threadIdx.x;
    float v[4], e[4];
    float m = -3.0e38f;
    #pragma unroll
    for (int i = 0; i < 4; ++i) {
        int p = i * 64 + lane;
        if (p < NP) {
            int idx = b * NP + p;
            v[i] = spart[idx] + spart[MROWS + idx] + spart[2 * MROWS + idx]
                 + spart[3 * MROWS + idx];
        } else v[i] = -3.0e38f;
        m = fmaxf(m, v[i]);
    }
    #pragma unroll
    for (int o = 1; o < 64; o <<= 1) m = fmaxf(m, __shfl_xor(m, o));
    float s = 0.f;
    #pragma unroll
    for (int i = 0; i < 4; ++i) {
        int p = i * 64 + lane;
        e[i] = (p < NP) ? __expf(v[i] - m) : 0.f;
        s += e[i];
    }
    #pragma unroll
    for (int o = 1; o < 64; o <<= 1) s += __shfl_xor(s, o);
    const float inv = 1.0f / s;
    #pragma unroll
    for (int i = 0; i < 4; ++i) {
        int p = i * 64 + lane;
        if (p < NP) alpha[b * NP + p] = e[i] * inv;
    }
}

// ---------------- context[b][f] = sum_p alpha[b][p] * X[b][p][f]  (fp32) ----------------
__global__ __launch_bounds__(128) void context_k(const float* __restrict__ X,
                                                 const float* __restrict__ alpha,
                                                 float* __restrict__ ctx) {
    __shared__ float al[NP];
    const int bid = blockIdx.x;
    const int b = 127 - (bid >> 2);
    const int chunk = bid & 3;
    const int tid = threadIdx.x;
    for (int i = tid; i < NP; i += 128) al[i] = alpha[b * NP + i];
    __syncthreads();
    const float4* Xp = reinterpret_cast<const float4*>(X + (size_t)b * NP * FEAT)
                       + chunk * 128 + tid;
    float4 a0 = {0,0,0,0}, a1 = {0,0,0,0};
    #pragma unroll 4
    for (int p = 0; p < NP; p += 2) {
        const float w0 = al[p], w1 = al[p + 1];
        const float4 x0 = Xp[(size_t)p * 512];
        const float4 x1 = Xp[(size_t)(p + 1) * 512];
        a0.x = fmaf(w0, x0.x, a0.x); a0.y = fmaf(w0, x0.y, a0.y);
        a0.z = fmaf(w0, x0.z, a0.z); a0.w = fmaf(w0, x0.w, a0.w);
        a1.x = fmaf(w1, x1.x, a1.x); a1.y = fmaf(w1, x1.y, a1.y);
        a1.z = fmaf(w1, x1.z, a1.z); a1.w = fmaf(w1, x1.w, a1.w);
    }
    float4 rr; rr.x = a0.x + a1.x; rr.y = a0.y + a1.y; rr.z = a0.z + a1.z; rr.w = a0.w + a1.w;
    *reinterpret_cast<float4*>(ctx + (size_t)b * FEAT + chunk * 512 + tid * 4) = rr;
}

extern "C" void kernel_launch(void* const* d_in, const int* in_sizes, int n_in,
                              void* d_out, int out_size, void* d_ws, size_t ws_size,
                              hipStream_t stream) {
    const float* enc    = (const float*)d_in[0];
    const float* hidden = (const float*)d_in[1];
    const float* We     = (const float*)d_in[2];
    const float* be     = (const float*)d_in[3];
    const float* Wd     = (const float*)d_in[4];
    const float* bd     = (const float*)d_in[5];
    const float* Wf     = (const float*)d_in[6];
    // d_in[7] = bf: additive constant to all scores -> softmax-invariant, unused.

    float* out   = (float*)d_out;
    float* ctx   = out;                  // [128*2048]
    float* alpha = out + NB * FEAT;      // [128*196]

    char* ws = (char*)d_ws;
    __bf16* Bp    = (__bf16*)ws;                                   // 2 MB packed We
    float*  decb  = (float*)(ws + (2u << 20));                     // 256 KB
    float*  spart = (float*)(ws + (2u << 20) + (256u << 10));      // 4 x 100 KB partials

    pack_we_k  <<<dim3(512), dim3(256), 0, stream>>>(We, Bp);
    dec_k      <<<dim3(64),  dim3(256), 0, stream>>>(hidden, Wd, bd, be, decb);
    enc_score_k<<<dim3(NBLK), dim3(256), 0, stream>>>(enc, Bp, decb, Wf, spart);
    softmax_k  <<<dim3(NB),  dim3(64),  0, stream>>>(spart, alpha);
    context_k  <<<dim3(512), dim3(128), 0, stream>>>(enc, alpha, ctx);
}